// Round 7
// baseline (167.135 us; speedup 1.0000x reference)
//
#include <hip/hip_runtime.h>
#include <hip/hip_bf16.h>

typedef __attribute__((ext_vector_type(8))) short short8;
typedef __attribute__((ext_vector_type(4))) float f32x4;
typedef __attribute__((ext_vector_type(4))) unsigned int u32x4;

#define B_DIM   8192
#define IN_DIM  2048
#define OUT_DIM 1024

#define BM 128
#define BN 128
#define BK 64
#define NK (IN_DIM / BK)           // 32 K-iters per pass
#define A_TILE_E (BM * BK)         // 8192 bf16 = 16 KB
#define B_TILE_E (BN * BK)         // 8192 bf16 = 16 KB
#define LDS_BYTES ((2 * A_TILE_E + 2 * B_TILE_E) * 2)   // 65536 = 64 KiB -> 2 blocks/CU

__device__ __forceinline__ unsigned short f2bf(float f) {
    union { float f; unsigned u; } v; v.f = f;
    unsigned u = v.u;
    unsigned r = (u + 0x7FFFu + ((u >> 16) & 1u)) >> 16;   // RNE
    return (unsigned short)r;
}

// Bw[o][i] = W[i][o] ; Ba[o][i] = 0.1*|W[i][o]|   (DELTA folded)
__global__ void prep_w(const float* __restrict__ W, unsigned short* __restrict__ Bw,
                       unsigned short* __restrict__ Ba) {
    __shared__ float tile[32][33];
    int o0 = blockIdx.x * 32;
    int i0 = blockIdx.y * 32;
    int tx = threadIdx.x, ty = threadIdx.y;   // 32 x 8
    #pragma unroll
    for (int r = 0; r < 4; ++r) {
        int ii = ty + r * 8;
        tile[ii][tx] = W[(size_t)(i0 + ii) * OUT_DIM + o0 + tx];
    }
    __syncthreads();
    #pragma unroll
    for (int r = 0; r < 4; ++r) {
        int oo = ty + r * 8;
        float wv = tile[tx][oo];
        Bw[(size_t)(o0 + oo) * IN_DIM + i0 + tx] = f2bf(wv);
        Ba[(size_t)(o0 + oo) * IN_DIM + i0 + tx] = f2bf(0.1f * fabsf(wv));
    }
}

// B staging: linear LDS dest, XOR-swizzled global SOURCE slot (rule 21).
// 128x64 tile = 16 KB = 4 rounds x (256 threads x 16 B).
__device__ __forceinline__ void stageB(const unsigned short* __restrict__ g,
                                       unsigned short* lds_dst,
                                       int col0, int k0, int tid) {
    #pragma unroll
    for (int r = 0; r < 4; ++r) {
        int c    = r * 256 + tid;                // 0..1023
        int row  = c >> 3;                       // 0..127
        int slot = (c & 7) ^ (row & 7);
        __builtin_amdgcn_global_load_lds(
            (const __attribute__((address_space(1))) void*)(g + (size_t)(col0 + row) * IN_DIM + k0 + slot * 8),
            (__attribute__((address_space(3))) void*)(lds_dst + (size_t)c * 8),
            16, 0, 0);
    }
}

// x -> regs: thread covers row r_ (0..127), k-half h (32 f32)
__device__ __forceinline__ void issue_x(const float* __restrict__ x, float4* xv,
                                        int row0, int r_, int h, int kc) {
    const float4* p = reinterpret_cast<const float4*>(
        x + (size_t)(row0 + r_) * IN_DIM + kc * BK + h * 32);
    #pragma unroll
    for (int j = 0; j < 8; ++j) xv[j] = p[j];
}

// regs -> bf16 A-tile in LDS, 8-slot XOR swizzle (slot = (4h+j) ^ (r&7));
// 8 consecutive lanes cover 8 distinct slots -> conflict-free b128 writes.
template<int PASS>
__device__ __forceinline__ void cvt_store(const float4* xv, unsigned short* Anxt,
                                          int r_, int h) {
    unsigned d[16];
    #pragma unroll
    for (int q = 0; q < 8; ++q) {
        float4 v = xv[q];
        float a, b, c, e;
        if (PASS == 0) {
            a = v.x >= -1.0f ? v.x : 0.0f;
            b = v.y >= -1.0f ? v.y : 0.0f;
            c = v.z >= -1.0f ? v.z : 0.0f;
            e = v.w >= -1.0f ? v.w : 0.0f;
        } else {
            a = -fabsf(v.x); b = -fabsf(v.y); c = -fabsf(v.z); e = -fabsf(v.w);
        }
        asm("v_cvt_pk_bf16_f32 %0, %1, %2" : "=v"(d[q * 2    ]) : "v"(a), "v"(b));
        asm("v_cvt_pk_bf16_f32 %0, %1, %2" : "=v"(d[q * 2 + 1]) : "v"(c), "v"(e));
    }
    int sw = r_ & 7;
    #pragma unroll
    for (int j = 0; j < 4; ++j) {
        int slot = (4 * h + j) ^ sw;
        *reinterpret_cast<u32x4*>(Anxt + r_ * BK + slot * 8) =
            (u32x4){d[j * 4], d[j * 4 + 1], d[j * 4 + 2], d[j * 4 + 3]};
    }
}

// inverse-swizzled fragment read (8-slot XOR, same as stage side)
__device__ __forceinline__ short8 read_frag(const unsigned short* buf, int row,
                                            int kk, int lq) {
    int sl = (kk * 4 + lq) ^ (row & 7);
    return *reinterpret_cast<const short8*>(buf + row * BK + (sl << 3));
}

// one K=64 iteration; fully static buffer/reg roles (rule #20)
#define ITER(T_, ACUR, ANXT, BCUR, BNXT, XISS, XCVT)                               \
  do {                                                                             \
    int t_ = (T_);                                                                 \
    bool dox_ = (t_ + 2 < NK);                                                     \
    bool dob_ = (t_ + 1 < NK);                                                     \
    if (dox_) issue_x(x, XISS, row0, r_, h, t_ + 2);                               \
    if (dob_) stageB(Bg, BNXT, col0, (t_ + 1) * BK, tid);                          \
    if (dox_)      asm volatile("s_waitcnt vmcnt(12)" ::: "memory");               \
    else if (dob_) asm volatile("s_waitcnt vmcnt(4)"  ::: "memory");               \
    else           asm volatile("s_waitcnt vmcnt(0)"  ::: "memory");               \
    short8 af0[4], bf0[4], af1[4], bf1[4];                                         \
    _Pragma("unroll") for (int m_ = 0; m_ < 4; ++m_)                               \
        af0[m_] = read_frag(ACUR, rowA + m_ * 16, 0, lq);                          \
    _Pragma("unroll") for (int n_ = 0; n_ < 4; ++n_)                               \
        bf0[n_] = read_frag(BCUR, rowB + n_ * 16, 0, lq);                          \
    _Pragma("unroll") for (int m_ = 0; m_ < 4; ++m_)                               \
        af1[m_] = read_frag(ACUR, rowA + m_ * 16, 1, lq);                          \
    _Pragma("unroll") for (int n_ = 0; n_ < 4; ++n_)                               \
        bf1[n_] = read_frag(BCUR, rowB + n_ * 16, 1, lq);                          \
    __builtin_amdgcn_s_setprio(1);                                                 \
    _Pragma("unroll") for (int m_ = 0; m_ < 4; ++m_)                               \
        _Pragma("unroll") for (int n_ = 0; n_ < 4; ++n_)                           \
            acc[m_][n_] = __builtin_amdgcn_mfma_f32_16x16x32_bf16(                 \
                af0[m_], bf0[n_], acc[m_][n_], 0, 0, 0);                           \
    _Pragma("unroll") for (int m_ = 0; m_ < 4; ++m_)                               \
        _Pragma("unroll") for (int n_ = 0; n_ < 4; ++n_)                           \
            acc[m_][n_] = __builtin_amdgcn_mfma_f32_16x16x32_bf16(                 \
                af1[m_], bf1[n_], acc[m_][n_], 0, 0, 0);                           \
    __builtin_amdgcn_s_setprio(0);                                                 \
    if (dob_) cvt_store<PASS>(XCVT, ANXT, r_, h);                                  \
    asm volatile("s_waitcnt lgkmcnt(0)" ::: "memory");                             \
    __builtin_amdgcn_s_barrier();                                                  \
  } while (0)

template<int PASS>
__device__ __forceinline__ void run_pass(const float* __restrict__ x,
                                         const unsigned short* __restrict__ Bg,
                                         unsigned short* sA, unsigned short* sB,
                                         f32x4 (&acc)[4][4],
                                         int row0, int col0, int tid,
                                         int rowA, int rowB, int lq, int r_, int h) {
    float4 xv0[8], xv1[8];
    // prologue: x(0),x(1) in flight; B(0) staged; A(0) written
    issue_x(x, xv0, row0, r_, h, 0);
    issue_x(x, xv1, row0, r_, h, 1);
    stageB(Bg, sB, col0, 0, tid);
    asm volatile("s_waitcnt vmcnt(12)" ::: "memory");   // x(0) retired
    cvt_store<PASS>(xv0, sA, r_, h);
    asm volatile("s_waitcnt lgkmcnt(0)" ::: "memory");
    __builtin_amdgcn_s_barrier();

    #pragma unroll 1
    for (int T = 0; T < NK; T += 2) {
        ITER(T,     sA,             sA + A_TILE_E, sB,             sB + B_TILE_E, xv0, xv1);
        ITER(T + 1, sA + A_TILE_E,  sA,            sB + B_TILE_E,  sB,            xv1, xv0);
    }
}

// out[b][o] = sum_i [ mask(x)*x*W + (-|x|)*(0.1|W|) ] + 1e-5
__global__ __launch_bounds__(256, 2) void gemm_fused(const float* __restrict__ x,
                                                     const unsigned short* __restrict__ Bw,
                                                     const unsigned short* __restrict__ Ba,
                                                     float* __restrict__ C) {
    extern __shared__ __align__(16) unsigned short smem[];
    unsigned short* sA = smem;                    // [2][8192]
    unsigned short* sB = smem + 2 * A_TILE_E;     // [2][8192]

    // XCD colocation (R3-verified): each XCD owns 8 contiguous by-panels
    int bid = blockIdx.x;
    int xcd = bid & 7;
    int idx = bid >> 3;            // 0..63
    int by  = xcd * 8 + (idx >> 3);
    int bx  = idx & 7;
    int row0 = by * BM;
    int col0 = bx * BN;

    int tid  = threadIdx.x;
    int lane = tid & 63;
    int w    = tid >> 6;           // 0..3
    int wr   = w >> 1;             // 0..1
    int wc   = w & 1;              // 0..1
    int lr   = lane & 15;
    int lq   = lane >> 4;          // 0..3
    int rowA = wr * 64 + lr;
    int rowB = wc * 64 + lr;
    int r_   = tid >> 1;           // A-staging row 0..127
    int h    = tid & 1;            // k-half

    f32x4 acc[4][4];
    #pragma unroll
    for (int m = 0; m < 4; ++m)
        #pragma unroll
        for (int n = 0; n < 4; ++n)
            acc[m][n] = (f32x4){0.f, 0.f, 0.f, 0.f};

    run_pass<0>(x, Bw, sA, sB, acc, row0, col0, tid, rowA, rowB, lq, r_, h);
    run_pass<1>(x, Ba, sA, sB, acc, row0, col0, tid, rowA, rowB, lq, r_, h);

    // epilogue: C/D layout col = lane&15, row = (lane>>4)*4 + reg
    #pragma unroll
    for (int m = 0; m < 4; ++m) {
        #pragma unroll
        for (int n = 0; n < 4; ++n) {
            int col  = col0 + wc * 64 + n * 16 + lr;
            int rowb = row0 + wr * 64 + m * 16 + lq * 4;
            #pragma unroll
            for (int j = 0; j < 4; ++j)
                C[(size_t)(rowb + j) * OUT_DIM + col] = acc[m][n][j] + 1e-5f;
        }
    }
}

extern "C" void kernel_launch(void* const* d_in, const int* in_sizes, int n_in,
                              void* d_out, int out_size, void* d_ws, size_t ws_size,
                              hipStream_t stream) {
    const float* x = (const float*)d_in[0];
    const float* W = (const float*)d_in[1];
    float* out = (float*)d_out;

    unsigned short* Bw = (unsigned short*)d_ws;                                   // 4 MB
    unsigned short* Ba = (unsigned short*)d_ws + (size_t)OUT_DIM * IN_DIM;        // +4 MB

    (void)hipFuncSetAttribute((const void*)gemm_fused,
                              hipFuncAttributeMaxDynamicSharedMemorySize, LDS_BYTES);

    prep_w<<<dim3(OUT_DIM / 32, IN_DIM / 32), dim3(32, 8), 0, stream>>>(W, Bw, Ba);
    gemm_fused<<<(B_DIM / BM) * (OUT_DIM / BN), 256, LDS_BYTES, stream>>>(x, Bw, Ba, out);
}

// Round 8
// 87.943 us; speedup vs baseline: 1.9005x; 1.9005x over previous
//
#include <hip/hip_runtime.h>
#include <hip/hip_bf16.h>

typedef __attribute__((ext_vector_type(8))) short short8;
typedef __attribute__((ext_vector_type(4))) float f32x4;
typedef __attribute__((ext_vector_type(2))) unsigned int u32x2;

#define B_DIM   8192
#define IN_DIM  2048
#define OUT_DIM 1024

#define BM 256
#define BN 128
#define KS 32                      // K-step per iteration
#define NT (IN_DIM / KS)           // 64 iterations
#define A_VAR_E (BM * KS)          // 8192 elems = 16 KB per variant
#define A_BUF_E (2 * A_VAR_E)      // xm + na = 32 KB per buffer
#define B_VAR_E (BN * KS)          // 4096 elems = 8 KB per variant
#define B_BUF_E (2 * B_VAR_E)      // Bw + Ba = 16 KB per buffer
#define LDS_BYTES ((2 * A_BUF_E + 2 * B_BUF_E) * 2)   // 98304 = 96 KiB

__device__ __forceinline__ unsigned short f2bf(float f) {
    union { float f; unsigned u; } v; v.f = f;
    unsigned u = v.u;
    unsigned r = (u + 0x7FFFu + ((u >> 16) & 1u)) >> 16;   // RNE
    return (unsigned short)r;
}

// Bw[o][i] = W[i][o] ; Ba[o][i] = 0.1*|W[i][o]|   (DELTA folded)
__global__ void prep_w(const float* __restrict__ W, unsigned short* __restrict__ Bw,
                       unsigned short* __restrict__ Ba) {
    __shared__ float tile[32][33];
    int o0 = blockIdx.x * 32;
    int i0 = blockIdx.y * 32;
    int tx = threadIdx.x, ty = threadIdx.y;   // 32 x 8
    #pragma unroll
    for (int r = 0; r < 4; ++r) {
        int ii = ty + r * 8;
        tile[ii][tx] = W[(size_t)(i0 + ii) * OUT_DIM + o0 + tx];
    }
    __syncthreads();
    #pragma unroll
    for (int r = 0; r < 4; ++r) {
        int oo = ty + r * 8;
        float wv = tile[tx][oo];
        Bw[(size_t)(o0 + oo) * IN_DIM + i0 + tx] = f2bf(wv);
        Ba[(size_t)(o0 + oo) * IN_DIM + i0 + tx] = f2bf(0.1f * fabsf(wv));
    }
}

// B staging: one variant tile 128x32 = 8 KB = 512 threads x 16 B (1 round).
// Linear LDS dest; XOR-swizzled global SOURCE slot (rule 21), 4 slots/row,
// swizzle s(row) = (row>>1)&3 -> 2-way (free) on frag reads.
__device__ __forceinline__ void stageB1(const unsigned short* __restrict__ g,
                                        unsigned short* lds_dst,
                                        int col0, int k0, int tid) {
    int row  = tid >> 2;                     // 0..127
    int slot = (tid & 3) ^ ((row >> 1) & 3);
    __builtin_amdgcn_global_load_lds(
        (const __attribute__((address_space(1))) void*)(g + (size_t)(col0 + row) * IN_DIM + k0 + slot * 8),
        (__attribute__((address_space(3))) void*)(lds_dst + (size_t)tid * 8),
        16, 0, 0);
}

// x -> regs, COALESCED: c = rnd*512+tid; 8 lanes cover one row's 32 f32
// (128 B contiguous per 8-lane group). 4 rounds cover 256 rows x 32 cols.
__device__ __forceinline__ void issue_x4(const float* __restrict__ x, float4* xv,
                                         int row0, int tid, int kc) {
    #pragma unroll
    for (int rnd = 0; rnd < 4; ++rnd) {
        int c    = rnd * 512 + tid;
        int row  = c >> 3;
        int col4 = c & 7;
        xv[rnd] = *reinterpret_cast<const float4*>(
            x + (size_t)(row0 + row) * IN_DIM + kc * KS + col4 * 4);
    }
}

// regs -> both bf16 A-variants in LDS. Each thread writes b64 (4 bf16) per
// variant per round; 8 lanes/row cover the full 64 B row (swizzle permutes
// 16 B slots within the row) -> wave writes 512 B contiguous, conflict-free.
__device__ __forceinline__ void cvt_store_dual(const float4* xv,
                                               unsigned short* Abuf, int tid) {
    #pragma unroll
    for (int rnd = 0; rnd < 4; ++rnd) {
        int c    = rnd * 512 + tid;
        int row  = c >> 3;
        int col4 = c & 7;
        int eoff = row * KS + ((col4 * 4) ^ (((row >> 1) & 3) * 8));
        float4 v = xv[rnd];
        float m0 = v.x >= -1.0f ? v.x : 0.0f;
        float m1 = v.y >= -1.0f ? v.y : 0.0f;
        float m2 = v.z >= -1.0f ? v.z : 0.0f;
        float m3 = v.w >= -1.0f ? v.w : 0.0f;
        float n0 = -fabsf(v.x), n1 = -fabsf(v.y);
        float n2 = -fabsf(v.z), n3 = -fabsf(v.w);
        unsigned xm0, xm1, na0, na1;
        asm("v_cvt_pk_bf16_f32 %0, %1, %2" : "=v"(xm0) : "v"(m0), "v"(m1));
        asm("v_cvt_pk_bf16_f32 %0, %1, %2" : "=v"(xm1) : "v"(m2), "v"(m3));
        asm("v_cvt_pk_bf16_f32 %0, %1, %2" : "=v"(na0) : "v"(n0), "v"(n1));
        asm("v_cvt_pk_bf16_f32 %0, %1, %2" : "=v"(na1) : "v"(n2), "v"(n3));
        *reinterpret_cast<u32x2*>(Abuf + eoff)           = (u32x2){xm0, xm1};
        *reinterpret_cast<u32x2*>(Abuf + A_VAR_E + eoff) = (u32x2){na0, na1};
    }
}

// fragment read, inverse swizzle: slot = lq ^ ((row>>1)&3), row = KS elems
__device__ __forceinline__ short8 read_frag(const unsigned short* buf, int row,
                                            int lq) {
    int sl = lq ^ ((row >> 1) & 3);
    return *reinterpret_cast<const short8*>(buf + row * KS + sl * 8);
}

// one K=32 iteration, single barrier region (R3 cadence)
#define ITER(T_, ACUR, ANXT, BCUR, BNXT, XISS, XCVT) do {                     \
    int t_ = (T_);                                                            \
    short8 fa0[4], fa1[4], fb0[4], fb1[4];                                    \
    _Pragma("unroll") for (int m_ = 0; m_ < 4; ++m_) {                        \
        fa0[m_] = read_frag((ACUR),           rowA + m_ * 16, lq);            \
        fa1[m_] = read_frag((ACUR) + A_VAR_E, rowA + m_ * 16, lq);            \
    }                                                                         \
    _Pragma("unroll") for (int n_ = 0; n_ < 4; ++n_) {                        \
        fb0[n_] = read_frag((BCUR),           rowB + n_ * 16, lq);            \
        fb1[n_] = read_frag((BCUR) + B_VAR_E, rowB + n_ * 16, lq);            \
    }                                                                         \
    if (t_ + 1 < NT) {                                                        \
        stageB1(Bw, (BNXT),           col0, (t_ + 1) * KS, tid);              \
        stageB1(Ba, (BNXT) + B_VAR_E, col0, (t_ + 1) * KS, tid);              \
    }                                                                         \
    if (t_ + 2 < NT) issue_x4(x, XISS, row0, tid, t_ + 2);                    \
    __builtin_amdgcn_s_setprio(1);                                            \
    _Pragma("unroll") for (int m_ = 0; m_ < 4; ++m_)                          \
        _Pragma("unroll") for (int n_ = 0; n_ < 4; ++n_)                      \
            acc[m_][n_] = __builtin_amdgcn_mfma_f32_16x16x32_bf16(            \
                fa0[m_], fb0[n_], acc[m_][n_], 0, 0, 0);                      \
    _Pragma("unroll") for (int m_ = 0; m_ < 4; ++m_)                          \
        _Pragma("unroll") for (int n_ = 0; n_ < 4; ++n_)                      \
            acc[m_][n_] = __builtin_amdgcn_mfma_f32_16x16x32_bf16(            \
                fa1[m_], fb1[n_], acc[m_][n_], 0, 0, 0);                      \
    __builtin_amdgcn_s_setprio(0);                                            \
    if (t_ + 1 < NT) {                                                        \
        cvt_store_dual((XCVT), (ANXT), tid);                                  \
        if (t_ + 2 < NT) asm volatile("s_waitcnt vmcnt(4)" ::: "memory");     \
        else             asm volatile("s_waitcnt vmcnt(0)" ::: "memory");     \
        asm volatile("s_waitcnt lgkmcnt(0)" ::: "memory");                    \
        __builtin_amdgcn_s_barrier();                                         \
    }                                                                         \
} while (0)

// out[b][o] = sum_i [ mask(x)*x*W + (-|x|)*(0.1|W|) ] + 1e-5
__global__ __launch_bounds__(512, 2) void gemm_fused(const float* __restrict__ x,
                                                     const unsigned short* __restrict__ Bw,
                                                     const unsigned short* __restrict__ Ba,
                                                     float* __restrict__ C) {
    extern __shared__ __align__(16) unsigned short smem[];
    unsigned short* sA = smem;                    // [2][A_BUF_E]
    unsigned short* sB = smem + 2 * A_BUF_E;      // [2][B_BUF_E]

    // XCD colocation (R3-verified): each XCD owns 4 contiguous by-panels
    int bid = blockIdx.x;
    int xcd = bid & 7;
    int idx = bid >> 3;            // 0..31
    int by  = xcd * 4 + (idx >> 3);
    int bx  = idx & 7;
    int row0 = by * BM;
    int col0 = bx * BN;

    int tid  = threadIdx.x;
    int lane = tid & 63;
    int w    = tid >> 6;           // 0..7
    int wr   = w >> 1;             // 0..3
    int wc   = w & 1;              // 0..1
    int lr   = lane & 15;
    int lq   = lane >> 4;          // 0..3
    int rowA = wr * 64 + lr;
    int rowB = wc * 64 + lr;

    f32x4 acc[4][4];
    #pragma unroll
    for (int m = 0; m < 4; ++m)
        #pragma unroll
        for (int n = 0; n < 4; ++n)
            acc[m][n] = (f32x4){0.f, 0.f, 0.f, 0.f};

    float4 xv0[4], xv1[4];

    // prologue: B(0) staged first (so vmcnt(4) retires it), x(0),x(1) issued,
    // A(0) written (compiler waits x(0) regs)
    stageB1(Bw, sB,           col0, 0, tid);
    stageB1(Ba, sB + B_VAR_E, col0, 0, tid);
    issue_x4(x, xv0, row0, tid, 0);
    issue_x4(x, xv1, row0, tid, 1);
    cvt_store_dual(xv0, sA, tid);
    asm volatile("s_waitcnt vmcnt(4)" ::: "memory");   // B(0) resident; x(1) in flight
    asm volatile("s_waitcnt lgkmcnt(0)" ::: "memory");
    __builtin_amdgcn_s_barrier();

    #pragma unroll 1
    for (int T = 0; T < NT; T += 2) {
        ITER(T,     sA,           sA + A_BUF_E, sB,           sB + B_BUF_E, xv0, xv1);
        ITER(T + 1, sA + A_BUF_E, sA,           sB + B_BUF_E, sB,           xv1, xv0);
    }

    // epilogue: C/D layout col = lane&15, row = (lane>>4)*4 + reg
    #pragma unroll
    for (int m = 0; m < 4; ++m) {
        #pragma unroll
        for (int n = 0; n < 4; ++n) {
            int col  = col0 + wc * 64 + n * 16 + lr;
            int rowb = row0 + wr * 64 + m * 16 + (lane >> 4) * 4;
            #pragma unroll
            for (int j = 0; j < 4; ++j)
                C[(size_t)(rowb + j) * OUT_DIM + col] = acc[m][n][j] + 1e-5f;
        }
    }
}

extern "C" void kernel_launch(void* const* d_in, const int* in_sizes, int n_in,
                              void* d_out, int out_size, void* d_ws, size_t ws_size,
                              hipStream_t stream) {
    const float* x = (const float*)d_in[0];
    const float* W = (const float*)d_in[1];
    float* out = (float*)d_out;

    unsigned short* Bw = (unsigned short*)d_ws;                                   // 4 MB
    unsigned short* Ba = (unsigned short*)d_ws + (size_t)OUT_DIM * IN_DIM;        // +4 MB

    (void)hipFuncSetAttribute((const void*)gemm_fused,
                              hipFuncAttributeMaxDynamicSharedMemorySize, LDS_BYTES);

    prep_w<<<dim3(OUT_DIM / 32, IN_DIM / 32), dim3(32, 8), 0, stream>>>(W, Bw, Ba);
    gemm_fused<<<(B_DIM / BM) * (OUT_DIM / BN), 512, LDS_BYTES, stream>>>(x, Bw, Ba, out);
}